// Round 12
// baseline (530.913 us; speedup 1.0000x reference)
//
#include <hip/hip_runtime.h>
#include <cfloat>
#include <cmath>

#define VOCAB 8192
#define MTOT 16384
#define CDIM 256
#define KSPLIT 8
#define TAU 0.1f
#define IDX_INF 0x7fffffff

typedef __attribute__((ext_vector_type(8))) short bf16x8;
typedef __attribute__((ext_vector_type(4))) float f32x4;

#define AS1 __attribute__((address_space(1)))
#define AS3 __attribute__((address_space(3)))

__device__ __forceinline__ void gl_lds16(const void* g, void* l) {
  __builtin_amdgcn_global_load_lds((const AS1 unsigned int*)g,
                                   (AS3 unsigned int*)l, 16, 0, 0);
}

__device__ inline ushort f2bf(float f) {
  unsigned u = __float_as_uint(f);
  unsigned r = (u + 0x7fffu + ((u >> 16) & 1u)) >> 16;
  return (ushort)r;
}

// merge other top-2 (ob,oi,os,osi) into mine (b,i,s,si); order by (value, index)
__device__ inline void top2_merge(float& b, int& i, float& s, int& si,
                                  float ob, int oi, float os, int osi) {
  if (ob < b || (ob == b && oi < i)) {
    if (b < os || (b == os && i < osi)) { s = b; si = i; }
    else { s = os; si = osi; }
    b = ob; i = oi;
  } else {
    if (ob < s || (ob == s && oi < si)) { s = ob; si = oi; }
  }
}

// ---------------- enorm: ||e_k||^2 fp32 + exact fp64 ----------------
__global__ void vq_enorm_kernel(const float* __restrict__ emb,
                                float* __restrict__ enorm,
                                double* __restrict__ enormd) {
  __shared__ double sd[4][64];
  int tid = threadIdx.x;
  int kk = tid & 63, cg = tid >> 6;
  int k = blockIdx.x * 64 + kk;
  double s = 0.0;
  for (int c = cg * 64; c < cg * 64 + 64; ++c) {
    float v = emb[(size_t)c * VOCAB + k];
    s += (double)v * (double)v;
  }
  sd[cg][kk] = s;
  __syncthreads();
  if (cg == 0) {
    double t = sd[0][kk] + sd[1][kk] + sd[2][kk] + sd[3][kk];
    enorm[k] = (float)t;
    enormd[k] = t;
  }
}

// ---------------- fused: transpose emb -> embT fp32 AND emit eb bf16 granules ----------------
// eb layout: per sp 64 sub-chunks (cg*4+kc) of 512 granules (8 KB).
// sub-chunk granule index = ks*256 + r*8 + s where code c_local = k&63, r=c_local>>1,
// s = ((c_local&1)<<2)|((lg + r)&3); dims = kc*64 + ks*32 + lg*8.
__global__ void vq_prep_embT_kernel(const float* __restrict__ emb,
                                    float* __restrict__ embT,
                                    ushort* __restrict__ eb) {
  __shared__ float t[32][33];
  int bc = blockIdx.x & 7;    // dims block of 32
  int bk = blockIdx.x >> 3;   // code block of 32
  int lx = threadIdx.x & 31, lyq = threadIdx.x >> 5;
#pragma unroll
  for (int yy = 0; yy < 4; ++yy) {
    int y = lyq * 4 + yy;
    t[y][lx] = emb[(size_t)(bc * 32 + y) * VOCAB + bk * 32 + lx];
  }
  __syncthreads();
#pragma unroll
  for (int yy = 0; yy < 4; ++yy) {
    int y = lyq * 4 + yy;
    embT[(size_t)(bk * 32 + y) * CDIM + bc * 32 + lx] = t[lx][y];
  }
  // granule emission: 128 granules (32 codes x 4 lg) for this (bk, bc) tile
  if (threadIdx.x < 128) {
    int cx = threadIdx.x >> 2, lg = threadIdx.x & 3;
    int k = bk * 32 + cx;
    int sp = k >> 10;
    int cg = (k >> 6) & 15;
    int c_local = k & 63;
    int kc = bc >> 1, ks = bc & 1;
    int r = c_local >> 1;
    int s = ((c_local & 1) << 2) | ((lg + r) & 3);
    size_t gi = ((size_t)(sp * 64 + cg * 4 + kc)) * 512 + ks * 256 + r * 8 + s;
    bf16x8 h;
#pragma unroll
    for (int j = 0; j < 8; ++j) h[j] = (short)f2bf(t[lg * 8 + j][cx]);
    *(bf16x8*)(eb + gi * 8) = h;
  }
}

// ---------------- pack -2x -> bf16 register-frag-ordered strips ----------------
// granule u: strip = u>>11 (64 rows); f = (u>>6)&31 = mf*8+kg; lane = u&63.
// row = strip*64 + mf*16 + (lane&15); dims = kg*32 + (lane>>4)*8
__global__ void vq_pack_x_kernel(const float* __restrict__ x,
                                 ushort* __restrict__ xb) {
  int u = blockIdx.x * 256 + threadIdx.x;
  int strip = u >> 11;
  int f = (u >> 6) & 31;
  int lane = u & 63;
  int mf = f >> 3, kg = f & 7;
  int lg = lane >> 4, l15 = lane & 15;
  int row = strip * 64 + mf * 16 + l15;
  int dims = kg * 32 + lg * 8;
  const float* src = x + (size_t)row * CDIM + dims;
  float4 v0 = *(const float4*)src;
  float4 v1 = *(const float4*)(src + 4);
  float a[8] = {v0.x, v0.y, v0.z, v0.w, v1.x, v1.y, v1.z, v1.w};
  bf16x8 h;
#pragma unroll
  for (int j = 0; j < 8; ++j) h[j] = (short)f2bf(-2.0f * a[j]);
  *(bf16x8*)(xb + (size_t)u * 8) = h;
}

// ---------------- dist: A in registers, 16KB periods, counted-vmcnt ring ----------------
#define WAIT4 asm volatile("s_waitcnt vmcnt(4) lgkmcnt(0)" ::: "memory")
#define WAIT0 asm volatile("s_waitcnt vmcnt(0) lgkmcnt(0)" ::: "memory")
#define WAITL asm volatile("s_waitcnt lgkmcnt(0)" ::: "memory")

#define STAGE_CHUNK(TT, BB)                                                    \
  { const ushort* _src = ebb + (size_t)(TT) * 8192;                            \
    _Pragma("unroll")                                                          \
    for (int i = 0; i < 4; ++i)                                                \
      gl_lds16(_src + (wid * 4 + i) * 512 + lane * 8,                          \
               &Bring[BB][(wid * 4 + i) * 512]); }

#define PERIOD(T, PB, H, DO_STAGE, WAIT_SEL)                                   \
  { if (DO_STAGE) STAGE_CHUNK((T) + 2, ((PB) + 2) & 3)                         \
    if ((H) == 0) {                                                            \
      _Pragma("unroll") for (int mf = 0; mf < 4; ++mf)                         \
      _Pragma("unroll") for (int nf = 0; nf < 4; ++nf)                         \
        acc[mf][nf] = (f32x4)0.f;                                              \
    }                                                                          \
    { const char* Bb = (const char*)&Bring[PB][0];                             \
      _Pragma("unroll") for (int ks = 0; ks < 4; ++ks) {                       \
        bf16x8 bfr[4];                                                         \
        _Pragma("unroll") for (int nf = 0; nf < 4; ++nf)                       \
          bfr[nf] = *(const bf16x8*)(Bb + ks * 4096 + offB[nf]);               \
        _Pragma("unroll") for (int mf = 0; mf < 4; ++mf)                       \
        _Pragma("unroll") for (int nf = 0; nf < 4; ++nf)                       \
          acc[mf][nf] = __builtin_amdgcn_mfma_f32_16x16x32_bf16(               \
              af[mf][(H) * 4 + ks], bfr[nf], acc[mf][nf], 0, 0, 0);            \
      } }                                                                      \
    if ((H) == 1) {                                                            \
      int cg = (T) >> 1;                                                       \
      float enf[4];                                                            \
      _Pragma("unroll") for (int nf = 0; nf < 4; ++nf)                         \
        enf[nf] = enLds[cg * 64 + nf * 16 + l15];                              \
      _Pragma("unroll") for (int nf = 0; nf < 4; ++nf) {                       \
        int n = sp * 1024 + cg * 64 + nf * 16 + l15;                           \
        _Pragma("unroll") for (int mf = 0; mf < 4; ++mf)                       \
        _Pragma("unroll") for (int r = 0; r < 4; ++r) {                        \
          float d = acc[mf][nf][r] + enf[nf];                                  \
          int s = mf * 4 + r;                                                  \
          if (d < bv[s]) { sv[s] = bv[s]; si[s] = bi[s]; bv[s] = d; bi[s] = n; } \
          else if (d < sv[s]) { sv[s] = d; si[s] = n; }                        \
        } }                                                                    \
    }                                                                          \
    __builtin_amdgcn_sched_barrier(0);                                         \
    WAIT_SEL;                                                                  \
    __builtin_amdgcn_sched_barrier(0);                                         \
    __builtin_amdgcn_s_barrier();                                              \
    __builtin_amdgcn_sched_barrier(0); }

__global__ __launch_bounds__(256, 2) void vq_dist_kernel(
    const ushort* __restrict__ xb, const ushort* __restrict__ eb,
    const float* __restrict__ enorm,
    float4* __restrict__ pkd, int4* __restrict__ pki) {
  __shared__ ushort Bring[4][8192];   // 4 x 16 KB ring
  __shared__ float enLds[1024];       // 4 KB

  const int tid = threadIdx.x;
  const int lane = tid & 63, wid = tid >> 6;
  const int l15 = lane & 15, lg = lane >> 4;
  const int rb = blockIdx.x >> 3, sp = blockIdx.x & 7;
  const int mw = rb * 256 + wid * 64;   // this wave's first row

  const ushort* ebb = eb + (size_t)sp * 262144;

  // --- prologue: enorm->LDS, A->regs, chunks 0,1 (issue order pinned) ---
  gl_lds16(enorm + sp * 1024 + wid * 256 + lane * 4, &enLds[wid * 256]);
  __builtin_amdgcn_sched_barrier(0);
  bf16x8 af[4][8];
  {
    const bf16x8* xs4 = (const bf16x8*)xb + (size_t)(rb * 4 + wid) * 2048 + lane;
#pragma unroll
    for (int mf = 0; mf < 4; ++mf)
#pragma unroll
      for (int kg = 0; kg < 8; ++kg)
        af[mf][kg] = xs4[(mf * 8 + kg) * 64];
  }
  __builtin_amdgcn_sched_barrier(0);
  STAGE_CHUNK(0, 0)
  STAGE_CHUNK(1, 1)
  __builtin_amdgcn_sched_barrier(0);
  asm volatile("s_waitcnt vmcnt(4)" ::: "memory");  // enorm+A+chunk0 done; chunk1 in flight
  __builtin_amdgcn_sched_barrier(0);
  __builtin_amdgcn_s_barrier();
  __builtin_amdgcn_sched_barrier(0);

  // hoisted B LDS byte offsets (pair-swizzle, proven conflict-free)
  uint offB[4];
#pragma unroll
  for (int nf = 0; nf < 4; ++nf) {
    int c = nf * 16 + l15;
    int r = c >> 1;
    int s = ((c & 1) << 2) | ((lg + r) & 3);
    offB[nf] = r * 128 + s * 16;
  }

  float bv[16], sv[16];
  int bi[16], si[16];
#pragma unroll
  for (int s = 0; s < 16; ++s) {
    bv[s] = FLT_MAX; sv[s] = FLT_MAX; bi[s] = 0; si[s] = 0;
  }

  f32x4 acc[4][4];

  // main: 28 periods in groups of 4 (buffer index == period&3, static)
  for (int it = 0; it < 7; ++it) {
    const int t0 = it * 4;
    PERIOD(t0 + 0, 0, 0, true, WAIT4)
    PERIOD(t0 + 1, 1, 1, true, WAIT4)
    PERIOD(t0 + 2, 2, 0, true, WAIT4)
    PERIOD(t0 + 3, 3, 1, true, WAIT4)
  }
  // tail t = 28..31
  PERIOD(28, 0, 0, true, WAIT4)    // stages chunk 30
  PERIOD(29, 1, 1, true, WAIT4)    // stages chunk 31
  PERIOD(30, 2, 0, false, WAIT0)
  PERIOD(31, 3, 1, false, WAITL)

  // per-row merge of per-stream top-2s across the 16 column-lanes
#pragma unroll
  for (int mf = 0; mf < 4; ++mf)
#pragma unroll
    for (int r = 0; r < 4; ++r) {
      int s = mf * 4 + r;
      float b = bv[s], sec = sv[s];
      int i = bi[s], s2i = si[s];
#pragma unroll
      for (int m = 1; m < 16; m <<= 1) {
        float ob = __shfl_xor(b, m, 64);
        float os = __shfl_xor(sec, m, 64);
        int oi = __shfl_xor(i, m, 64);
        int osi = __shfl_xor(s2i, m, 64);
        top2_merge(b, i, sec, s2i, ob, oi, os, osi);
      }
      if (l15 == 0) {
        int row = mw + mf * 16 + lg * 4 + r;
        // pad with FLT_MAX dists + duplicated valid indices (gather-safe)
        pkd[(size_t)sp * MTOT + row] = make_float4(b, sec, FLT_MAX, FLT_MAX);
        pki[(size_t)sp * MTOT + row] = make_int4(i, s2i, i, s2i);
      }
    }
}

// ---------------- merge 32 candidates + fp64 rescue + gather (1 wave / row) ----------------
__global__ void vq_gather_kernel(
    const float* __restrict__ x, const float* __restrict__ embT,
    const double* __restrict__ enormd,
    const float4* __restrict__ pkd, const int4* __restrict__ pki,
    float* __restrict__ out, int* __restrict__ counts, float* __restrict__ ssep) {
  const int wid = threadIdx.x >> 6, lane = threadIdx.x & 63;
  const int m = blockIdx.x * 4 + wid;

  const float4 xq = *(const float4*)(x + (size_t)m * CDIM + lane * 4);

  float bd = FLT_MAX, sd = FLT_MAX;
  int bidx = IDX_INF;
#pragma unroll
  for (int sp2 = 0; sp2 < KSPLIT; ++sp2) {
    float4 dv = pkd[(size_t)sp2 * MTOT + m];
    int4 iv = pki[(size_t)sp2 * MTOT + m];
    float ds[4] = {dv.x, dv.y, dv.z, dv.w};
    int is[4] = {iv.x, iv.y, iv.z, iv.w};
#pragma unroll
    for (int j = 0; j < 4; ++j) {
      float dj = ds[j];
      int ij = is[j];
      if (dj < bd || (dj == bd && ij < bidx)) { sd = bd; bd = dj; bidx = ij; }
      else sd = fminf(sd, dj);
    }
  }
  int best = bidx;
  if (sd - bd < TAU) {   // ambiguous: exact fp64 over all candidates (wave-uniform)
    double bD = DBL_MAX;
    int bn = IDX_INF;
    for (int sp2 = 0; sp2 < KSPLIT; ++sp2) {
      int4 iv = pki[(size_t)sp2 * MTOT + m];
      int is[4] = {iv.x, iv.y, iv.z, iv.w};
#pragma unroll
      for (int j = 0; j < 4; ++j) {
        int cj = is[j];
        const float4 ev = *(const float4*)(embT + (size_t)cj * CDIM + lane * 4);
        double p = (double)xq.x * ev.x + (double)xq.y * ev.y
                 + (double)xq.z * ev.z + (double)xq.w * ev.w;
#pragma unroll
        for (int off = 1; off < 64; off <<= 1) p += __shfl_xor(p, off, 64);
        double dj = enormd[cj] - 2.0 * p;
        if (dj < bD || (dj == bD && cj < bn)) { bD = dj; bn = cj; }
      }
    }
    best = bn;
  }
  const float4 ev = *(const float4*)(embT + (size_t)best * CDIM + lane * 4);
  *(float4*)(out + (size_t)m * CDIM + lane * 4) = ev;
  float dx = ev.x - xq.x, dy = ev.y - xq.y, dz = ev.z - xq.z, dw = ev.w - xq.w;
  float v = dx * dx + dy * dy + dz * dz + dw * dw;
#pragma unroll
  for (int off = 32; off > 0; off >>= 1) v += __shfl_down(v, off, 64);
  if (lane == 0) {
    ssep[m] = v;
    atomicAdd(&counts[best], 1);
  }
}

// ---------------- loss + perplexity, single fused kernel (1 block) ----------------
__global__ void vq_final_kernel(const float* __restrict__ ssep,
                                const int* __restrict__ counts,
                                float* __restrict__ out) {
  __shared__ double red[256];
  const int tid = threadIdx.x;
  double s = 0.0;
  for (int i = tid; i < MTOT; i += 256) s += (double)ssep[i];
  red[tid] = s;
  __syncthreads();
  for (int off = 128; off > 0; off >>= 1) {
    if (tid < off) red[tid] += red[tid + off];
    __syncthreads();
  }
  double sse = red[0];
  __syncthreads();
  double e = 0.0;
  for (int k = tid; k < VOCAB; k += 256) {
    double p = (double)counts[k] / (double)MTOT;
    e += p * log(p + 1e-10);
  }
  red[tid] = e;
  __syncthreads();
  for (int off = 128; off > 0; off >>= 1) {
    if (tid < off) red[tid] += red[tid + off];
    __syncthreads();
  }
  if (tid == 0) {
    out[(size_t)MTOT * CDIM] = (float)(1.25 * sse / (double)((size_t)MTOT * CDIM));
    out[(size_t)MTOT * CDIM + 1] = (float)exp(-red[0]);
  }
}

extern "C" void kernel_launch(void* const* d_in, const int* in_sizes, int n_in,
                              void* d_out, int out_size, void* d_ws, size_t ws_size,
                              hipStream_t stream) {
  const float* x = (const float*)d_in[0];
  const float* emb = (const float*)d_in[1];
  float* out = (float*)d_out;
  char* ws = (char*)d_ws;

  // workspace layout (bytes)
  double* enormd = (double*)(ws);                 //        0: 65536
  float* enorm   = (float*)(ws + 65536);          //    65536: 32768
  float4* pkd    = (float4*)(ws + 98304);         //    98304: 2097152
  int4* pki      = (int4*)(ws + 2195456);         //  2195456: 2097152
  int* counts    = (int*)(ws + 4292608);          //  4292608: 32768
  float* ssep    = (float*)(ws + 4325376);        //  4325376: 65536
  float* embT    = (float*)(ws + 4391936);        //  4391936: 8388608
  ushort* xb     = (ushort*)(ws + 12780544);      // 12780544: 8388608
  ushort* eb     = (ushort*)(ws + 21169152);      // 21169152: 4194304
  // total 25363456 bytes (< 35 MB proven available in rounds 1-11)

  hipMemsetAsync(counts, 0, VOCAB * sizeof(int), stream);
  vq_enorm_kernel<<<VOCAB / 64, 256, 0, stream>>>(emb, enorm, enormd);
  vq_prep_embT_kernel<<<(VOCAB / 32) * (CDIM / 32), 256, 0, stream>>>(emb, embT, eb);
  vq_pack_x_kernel<<<(MTOT * CDIM / 8) / 256, 256, 0, stream>>>(x, xb);
  vq_dist_kernel<<<(MTOT / 256) * KSPLIT, 256, 0, stream>>>(xb, eb, enorm, pkd, pki);
  vq_gather_kernel<<<MTOT / 4, 256, 0, stream>>>(x, embT, enormd, pkd, pki,
                                                 out, counts, ssep);
  vq_final_kernel<<<1, 256, 0, stream>>>(ssep, counts, out);
}

// Round 13
// 269.391 us; speedup vs baseline: 1.9708x; 1.9708x over previous
//
#include <hip/hip_runtime.h>
#include <cfloat>
#include <cmath>

#define VOCAB 8192
#define MTOT 16384
#define CDIM 256
#define KSPLIT 8
#define TAU 0.1f
#define IDX_INF 0x7fffffff

typedef __attribute__((ext_vector_type(8))) short bf16x8;
typedef __attribute__((ext_vector_type(4))) float f32x4;

#define AS1 __attribute__((address_space(1)))
#define AS3 __attribute__((address_space(3)))

__device__ __forceinline__ void gl_lds16(const void* g, void* l) {
  __builtin_amdgcn_global_load_lds((const AS1 unsigned int*)g,
                                   (AS3 unsigned int*)l, 16, 0, 0);
}

__device__ inline ushort f2bf(float f) {
  unsigned u = __float_as_uint(f);
  unsigned r = (u + 0x7fffu + ((u >> 16) & 1u)) >> 16;
  return (ushort)r;
}

// merge other top-2 (ob,oi,os,osi) into mine (b,i,s,si); order by (value, index)
__device__ inline void top2_merge(float& b, int& i, float& s, int& si,
                                  float ob, int oi, float os, int osi) {
  if (ob < b || (ob == b && oi < i)) {
    if (b < os || (b == os && i < osi)) { s = b; si = i; }
    else { s = os; si = osi; }
    b = ob; i = oi;
  } else {
    if (ob < s || (ob == s && oi < si)) { s = ob; si = oi; }
  }
}

// ---------------- enorm: ||e_k||^2 fp32 + exact fp64 ----------------
__global__ void vq_enorm_kernel(const float* __restrict__ emb,
                                float* __restrict__ enorm,
                                double* __restrict__ enormd) {
  __shared__ double sd[4][64];
  int tid = threadIdx.x;
  int kk = tid & 63, cg = tid >> 6;
  int k = blockIdx.x * 64 + kk;
  double s = 0.0;
  for (int c = cg * 64; c < cg * 64 + 64; ++c) {
    float v = emb[(size_t)c * VOCAB + k];
    s += (double)v * (double)v;
  }
  sd[cg][kk] = s;
  __syncthreads();
  if (cg == 0) {
    double t = sd[0][kk] + sd[1][kk] + sd[2][kk] + sd[3][kk];
    enorm[k] = (float)t;
    enormd[k] = t;
  }
}

// ---------------- fused: transpose emb -> embT fp32 AND emit eb bf16 granules ----------------
// eb layout: per sp 64 sub-chunks (cg*4+kc) of 512 granules (8 KB).
// sub-chunk granule index = ks*256 + r*8 + s where code c_local = k&63, r=c_local>>1,
// s = ((c_local&1)<<2)|((lg + r)&3); dims = kc*64 + ks*32 + lg*8.
__global__ void vq_prep_embT_kernel(const float* __restrict__ emb,
                                    float* __restrict__ embT,
                                    ushort* __restrict__ eb) {
  __shared__ float t[32][33];
  int bc = blockIdx.x & 7;    // dims block of 32
  int bk = blockIdx.x >> 3;   // code block of 32
  int lx = threadIdx.x & 31, lyq = threadIdx.x >> 5;
#pragma unroll
  for (int yy = 0; yy < 4; ++yy) {
    int y = lyq * 4 + yy;
    t[y][lx] = emb[(size_t)(bc * 32 + y) * VOCAB + bk * 32 + lx];
  }
  __syncthreads();
#pragma unroll
  for (int yy = 0; yy < 4; ++yy) {
    int y = lyq * 4 + yy;
    embT[(size_t)(bk * 32 + y) * CDIM + bc * 32 + lx] = t[lx][y];
  }
  // granule emission: 128 granules (32 codes x 4 lg) for this (bk, bc) tile
  if (threadIdx.x < 128) {
    int cx = threadIdx.x >> 2, lg = threadIdx.x & 3;
    int k = bk * 32 + cx;
    int sp = k >> 10;
    int cg = (k >> 6) & 15;
    int c_local = k & 63;
    int kc = bc >> 1, ks = bc & 1;
    int r = c_local >> 1;
    int s = ((c_local & 1) << 2) | ((lg + r) & 3);
    size_t gi = ((size_t)(sp * 64 + cg * 4 + kc)) * 512 + ks * 256 + r * 8 + s;
    bf16x8 h;
#pragma unroll
    for (int j = 0; j < 8; ++j) h[j] = (short)f2bf(t[lg * 8 + j][cx]);
    *(bf16x8*)(eb + gi * 8) = h;
  }
}

// ---------------- pack -2x -> bf16 register-frag-ordered strips ----------------
// granule u: strip = u>>11 (64 rows); f = (u>>6)&31 = mf*8+kg; lane = u&63.
// row = strip*64 + mf*16 + (lane&15); dims = kg*32 + (lane>>4)*8
__global__ void vq_pack_x_kernel(const float* __restrict__ x,
                                 ushort* __restrict__ xb) {
  int u = blockIdx.x * 256 + threadIdx.x;
  int strip = u >> 11;
  int f = (u >> 6) & 31;
  int lane = u & 63;
  int mf = f >> 3, kg = f & 7;
  int lg = lane >> 4, l15 = lane & 15;
  int row = strip * 64 + mf * 16 + l15;
  int dims = kg * 32 + lg * 8;
  const float* src = x + (size_t)row * CDIM + dims;
  float4 v0 = *(const float4*)src;
  float4 v1 = *(const float4*)(src + 4);
  float a[8] = {v0.x, v0.y, v0.z, v0.w, v1.x, v1.y, v1.z, v1.w};
  bf16x8 h;
#pragma unroll
  for (int j = 0; j < 8; ++j) h[j] = (short)f2bf(-2.0f * a[j]);
  *(bf16x8*)(xb + (size_t)u * 8) = h;
}

// ---------------- dist: A in registers, 16KB periods, counted-vmcnt ring ----------------
#define WAIT4 asm volatile("s_waitcnt vmcnt(4) lgkmcnt(0)" ::: "memory")
#define WAIT0 asm volatile("s_waitcnt vmcnt(0) lgkmcnt(0)" ::: "memory")
#define WAITL asm volatile("s_waitcnt lgkmcnt(0)" ::: "memory")

#define STAGE_CHUNK(TT, BB)                                                    \
  { const ushort* _src = ebb + (size_t)(TT) * 8192;                            \
    _Pragma("unroll")                                                          \
    for (int i = 0; i < 4; ++i)                                                \
      gl_lds16(_src + (wid * 4 + i) * 512 + lane * 8,                          \
               &Bring[BB][(wid * 4 + i) * 512]); }

#define PERIOD(T, PB, H, DO_STAGE, WAIT_SEL)                                   \
  { if (DO_STAGE) STAGE_CHUNK((T) + 2, ((PB) + 2) & 3)                         \
    if ((H) == 0) {                                                            \
      _Pragma("unroll") for (int mf = 0; mf < 4; ++mf)                         \
      _Pragma("unroll") for (int nf = 0; nf < 4; ++nf)                         \
        acc[mf][nf] = (f32x4)0.f;                                              \
    }                                                                          \
    { const char* Bb = (const char*)&Bring[PB][0];                             \
      _Pragma("unroll") for (int ks = 0; ks < 4; ++ks) {                       \
        bf16x8 bfr[4];                                                         \
        _Pragma("unroll") for (int nf = 0; nf < 4; ++nf)                       \
          bfr[nf] = *(const bf16x8*)(Bb + ks * 4096 + offB[nf]);               \
        _Pragma("unroll") for (int mf = 0; mf < 4; ++mf)                       \
        _Pragma("unroll") for (int nf = 0; nf < 4; ++nf)                       \
          acc[mf][nf] = __builtin_amdgcn_mfma_f32_16x16x32_bf16(               \
              af[mf][(H) * 4 + ks], bfr[nf], acc[mf][nf], 0, 0, 0);            \
      } }                                                                      \
    if ((H) == 1) {                                                            \
      int cg = (T) >> 1;                                                       \
      float enf[4];                                                            \
      _Pragma("unroll") for (int nf = 0; nf < 4; ++nf)                         \
        enf[nf] = enLds[cg * 64 + nf * 16 + l15];                              \
      _Pragma("unroll") for (int nf = 0; nf < 4; ++nf) {                       \
        int n = sp * 1024 + cg * 64 + nf * 16 + l15;                           \
        _Pragma("unroll") for (int mf = 0; mf < 4; ++mf)                       \
        _Pragma("unroll") for (int r = 0; r < 4; ++r) {                        \
          float d = acc[mf][nf][r] + enf[nf];                                  \
          int s = mf * 4 + r;                                                  \
          if (d < bv[s]) { bv[s] = d; bi[s] = n; }                             \
        } }                                                                    \
    }                                                                          \
    __builtin_amdgcn_sched_barrier(0);                                         \
    WAIT_SEL;                                                                  \
    __builtin_amdgcn_sched_barrier(0);                                         \
    __builtin_amdgcn_s_barrier();                                              \
    __builtin_amdgcn_sched_barrier(0); }

__global__ __launch_bounds__(256, 2) void vq_dist_kernel(
    const ushort* __restrict__ xb, const ushort* __restrict__ eb,
    const float* __restrict__ enorm,
    float4* __restrict__ pkd, int4* __restrict__ pki) {
  __shared__ ushort Bring[4][8192];   // 4 x 16 KB ring
  __shared__ float enLds[1024];       // 4 KB

  const int tid = threadIdx.x;
  const int lane = tid & 63, wid = tid >> 6;
  const int l15 = lane & 15, lg = lane >> 4;
  const int rb = blockIdx.x >> 3, sp = blockIdx.x & 7;
  const int mw = rb * 256 + wid * 64;   // this wave's first row

  const ushort* ebb = eb + (size_t)sp * 262144;

  // --- prologue: enorm->LDS, A->regs, chunks 0,1 (issue order pinned) ---
  gl_lds16(enorm + sp * 1024 + wid * 256 + lane * 4, &enLds[wid * 256]);
  __builtin_amdgcn_sched_barrier(0);
  bf16x8 af[4][8];
  {
    const bf16x8* xs4 = (const bf16x8*)xb + (size_t)(rb * 4 + wid) * 2048 + lane;
#pragma unroll
    for (int mf = 0; mf < 4; ++mf)
#pragma unroll
      for (int kg = 0; kg < 8; ++kg)
        af[mf][kg] = xs4[(mf * 8 + kg) * 64];
  }
  __builtin_amdgcn_sched_barrier(0);
  STAGE_CHUNK(0, 0)
  STAGE_CHUNK(1, 1)
  __builtin_amdgcn_sched_barrier(0);
  asm volatile("s_waitcnt vmcnt(4)" ::: "memory");  // enorm+A+chunk0 done; chunk1 in flight
  __builtin_amdgcn_sched_barrier(0);
  __builtin_amdgcn_s_barrier();
  __builtin_amdgcn_sched_barrier(0);

  // hoisted B LDS byte offsets (pair-swizzle, proven conflict-free)
  uint offB[4];
#pragma unroll
  for (int nf = 0; nf < 4; ++nf) {
    int c = nf * 16 + l15;
    int r = c >> 1;
    int s = ((c & 1) << 2) | ((lg + r) & 3);
    offB[nf] = r * 128 + s * 16;
  }

  float bv[16];
  int bi[16];
#pragma unroll
  for (int s = 0; s < 16; ++s) { bv[s] = FLT_MAX; bi[s] = 0; }

  f32x4 acc[4][4];

  // main: 28 periods in groups of 4 (buffer index == period&3, static)
  for (int it = 0; it < 7; ++it) {
    PERIOD(it * 4 + 0, 0, 0, true, WAIT4)
    PERIOD(it * 4 + 1, 1, 1, true, WAIT4)
    PERIOD(it * 4 + 2, 2, 0, true, WAIT4)
    PERIOD(it * 4 + 3, 3, 1, true, WAIT4)
  }
  // tail t = 28..31
  PERIOD(28, 0, 0, true, WAIT4)    // stages chunk 30
  PERIOD(29, 1, 1, true, WAIT4)    // stages chunk 31
  PERIOD(30, 2, 0, false, WAIT0)
  PERIOD(31, 3, 1, false, WAITL)

  // per-row top-2 across the 16 column-lanes (from per-stream top-1s, r11-proven)
#pragma unroll
  for (int mf = 0; mf < 4; ++mf)
#pragma unroll
    for (int r = 0; r < 4; ++r) {
      int s = mf * 4 + r;
      float b = bv[s], sec = FLT_MAX;
      int i = bi[s], si = IDX_INF;
#pragma unroll
      for (int m = 1; m < 16; m <<= 1) {
        float ob = __shfl_xor(b, m, 64);
        float os = __shfl_xor(sec, m, 64);
        int oi = __shfl_xor(i, m, 64);
        int osi = __shfl_xor(si, m, 64);
        top2_merge(b, i, sec, si, ob, oi, os, osi);
      }
      if (l15 == 0) {
        int row = mw + mf * 16 + lg * 4 + r;
        // pad with FLT_MAX dists + duplicated valid indices (gather-safe)
        pkd[(size_t)sp * MTOT + row] = make_float4(b, sec, FLT_MAX, FLT_MAX);
        pki[(size_t)sp * MTOT + row] = make_int4(i, si, i, si);
      }
    }
}

// ---------------- merge 32 candidates + fp64 rescue + gather (1 wave / row) ----------------
__global__ void vq_gather_kernel(
    const float* __restrict__ x, const float* __restrict__ embT,
    const double* __restrict__ enormd,
    const float4* __restrict__ pkd, const int4* __restrict__ pki,
    float* __restrict__ out, int* __restrict__ counts, float* __restrict__ ssep) {
  const int wid = threadIdx.x >> 6, lane = threadIdx.x & 63;
  const int m = blockIdx.x * 4 + wid;

  const float4 xq = *(const float4*)(x + (size_t)m * CDIM + lane * 4);

  float bd = FLT_MAX, sd = FLT_MAX;
  int bidx = IDX_INF;
#pragma unroll
  for (int sp2 = 0; sp2 < KSPLIT; ++sp2) {
    float4 dv = pkd[(size_t)sp2 * MTOT + m];
    int4 iv = pki[(size_t)sp2 * MTOT + m];
    float ds[4] = {dv.x, dv.y, dv.z, dv.w};
    int is[4] = {iv.x, iv.y, iv.z, iv.w};
#pragma unroll
    for (int j = 0; j < 4; ++j) {
      float dj = ds[j];
      int ij = is[j];
      if (dj < bd || (dj == bd && ij < bidx)) { sd = bd; bd = dj; bidx = ij; }
      else sd = fminf(sd, dj);
    }
  }
  int best = bidx;
  if (sd - bd < TAU) {   // ambiguous: exact fp64 over all candidates (wave-uniform)
    double bD = DBL_MAX;
    int bn = IDX_INF;
    for (int sp2 = 0; sp2 < KSPLIT; ++sp2) {
      int4 iv = pki[(size_t)sp2 * MTOT + m];
      int is[4] = {iv.x, iv.y, iv.z, iv.w};
#pragma unroll
      for (int j = 0; j < 4; ++j) {
        int cj = is[j];
        const float4 ev = *(const float4*)(embT + (size_t)cj * CDIM + lane * 4);
        double p = (double)xq.x * ev.x + (double)xq.y * ev.y
                 + (double)xq.z * ev.z + (double)xq.w * ev.w;
#pragma unroll
        for (int off = 1; off < 64; off <<= 1) p += __shfl_xor(p, off, 64);
        double dj = enormd[cj] - 2.0 * p;
        if (dj < bD || (dj == bD && cj < bn)) { bD = dj; bn = cj; }
      }
    }
    best = bn;
  }
  const float4 ev = *(const float4*)(embT + (size_t)best * CDIM + lane * 4);
  *(float4*)(out + (size_t)m * CDIM + lane * 4) = ev;
  float dx = ev.x - xq.x, dy = ev.y - xq.y, dz = ev.z - xq.z, dw = ev.w - xq.w;
  float v = dx * dx + dy * dy + dz * dz + dw * dw;
#pragma unroll
  for (int off = 32; off > 0; off >>= 1) v += __shfl_down(v, off, 64);
  if (lane == 0) {
    ssep[m] = v;
    atomicAdd(&counts[best], 1);
  }
}

// ---------------- loss + perplexity, single fused kernel (1 block) ----------------
__global__ void vq_final_kernel(const float* __restrict__ ssep,
                                const int* __restrict__ counts,
                                float* __restrict__ out) {
  __shared__ double red[256];
  const int tid = threadIdx.x;
  double s = 0.0;
  for (int i = tid; i < MTOT; i += 256) s += (double)ssep[i];
  red[tid] = s;
  __syncthreads();
  for (int off = 128; off > 0; off >>= 1) {
    if (tid < off) red[tid] += red[tid + off];
    __syncthreads();
  }
  double sse = red[0];
  __syncthreads();
  double e = 0.0;
  for (int k = tid; k < VOCAB; k += 256) {
    double p = (double)counts[k] / (double)MTOT;
    e += p * log(p + 1e-10);
  }
  red[tid] = e;
  __syncthreads();
  for (int off = 128; off > 0; off >>= 1) {
    if (tid < off) red[tid] += red[tid + off];
    __syncthreads();
  }
  if (tid == 0) {
    out[(size_t)MTOT * CDIM] = (float)(1.25 * sse / (double)((size_t)MTOT * CDIM));
    out[(size_t)MTOT * CDIM + 1] = (float)exp(-red[0]);
  }
}

extern "C" void kernel_launch(void* const* d_in, const int* in_sizes, int n_in,
                              void* d_out, int out_size, void* d_ws, size_t ws_size,
                              hipStream_t stream) {
  const float* x = (const float*)d_in[0];
  const float* emb = (const float*)d_in[1];
  float* out = (float*)d_out;
  char* ws = (char*)d_ws;

  // workspace layout (bytes)
  double* enormd = (double*)(ws);                 //        0: 65536
  float* enorm   = (float*)(ws + 65536);          //    65536: 32768
  float4* pkd    = (float4*)(ws + 98304);         //    98304: 2097152
  int4* pki      = (int4*)(ws + 2195456);         //  2195456: 2097152
  int* counts    = (int*)(ws + 4292608);          //  4292608: 32768
  float* ssep    = (float*)(ws + 4325376);        //  4325376: 65536
  float* embT    = (float*)(ws + 4391936);        //  4391936: 8388608
  ushort* xb     = (ushort*)(ws + 12780544);      // 12780544: 8388608
  ushort* eb     = (ushort*)(ws + 21169152);      // 21169152: 4194304
  // total 25363456 bytes (< 35 MB proven available in rounds 1-12)

  hipMemsetAsync(counts, 0, VOCAB * sizeof(int), stream);
  vq_enorm_kernel<<<VOCAB / 64, 256, 0, stream>>>(emb, enorm, enormd);
  vq_prep_embT_kernel<<<(VOCAB / 32) * (CDIM / 32), 256, 0, stream>>>(emb, embT, eb);
  vq_pack_x_kernel<<<(MTOT * CDIM / 8) / 256, 256, 0, stream>>>(x, xb);
  vq_dist_kernel<<<(MTOT / 256) * KSPLIT, 256, 0, stream>>>(xb, eb, enorm, pkd, pki);
  vq_gather_kernel<<<MTOT / 4, 256, 0, stream>>>(x, embT, enormd, pkd, pki,
                                                 out, counts, ssep);
  vq_final_kernel<<<1, 256, 0, stream>>>(ssep, counts, out);
}